// Round 2
// baseline (5090.598 us; speedup 1.0000x reference)
//
#include <hip/hip_runtime.h>
#include <hip/hip_bf16.h>

#define TT 4096
#define FF 80
#define HH 64
#define NB 128           // batch
#define TB 256           // timesteps per projection block
#define SB 32            // x rows staged per LDS buffer

__device__ __forceinline__ float sigm(float x) {
    return __builtin_amdgcn_rcpf(1.0f + __expf(-x));
}
__device__ __forceinline__ float tanh_f(float x) {
    return 1.0f - 2.0f * __builtin_amdgcn_rcpf(1.0f + __expf(2.0f * x));
}

__device__ __forceinline__ float ldv(const float* p) { return *p; }
__device__ __forceinline__ float ldv(const __hip_bfloat16* p) { return __bfloat162float(*p); }
__device__ __forceinline__ void stv(float* p, float v) { *p = v; }
__device__ __forceinline__ void stv(__hip_bfloat16* p, float v) { *p = __float2bfloat16(v); }

// ---------------------------------------------------------------------------
// Projection: PRE[dir][b][t][k] = b_ih[k]+b_hh[k] + sum_f w_ih[k][f] * x[b][t_eff][f]
// t_eff = t (fwd) or TT-1-t (bwd) -> scan always reads PRE sequentially in t.
// Fully parallel over (dir, b, t). Thread k owns gate k, w_ih row in registers.
// ---------------------------------------------------------------------------
template <typename ST>
__global__ __launch_bounds__(256)
void lstm_proj_kernel(const float* __restrict__ x,
                      const float* __restrict__ w_ih_f, const float* __restrict__ b_ih_f,
                      const float* __restrict__ b_hh_f,
                      const float* __restrict__ w_ih_b, const float* __restrict__ b_ih_b,
                      const float* __restrict__ b_hh_b,
                      ST* __restrict__ pre)            // [2][NB][TT][256]
{
    const int blk  = blockIdx.x;          // 2 * NB * (TT/TB)
    const int tile = blk & (TT / TB - 1); // 16 tiles
    const int bat  = (blk >> 4) & (NB - 1);
    const int dir  = blk >> 11;
    const int tid  = threadIdx.x;         // gate index k
    const int t0   = tile * TB;

    const float* __restrict__ w_ih = dir ? w_ih_b : w_ih_f;
    const float  bias = (dir ? b_ih_b[tid] + b_hh_b[tid] : b_ih_f[tid] + b_hh_f[tid]);

    float4 wi4[FF / 4];
    const float4* wr = reinterpret_cast<const float4*>(w_ih + tid * FF);
    #pragma unroll
    for (int q = 0; q < FF / 4; ++q) wi4[q] = wr[q];

    __shared__ float xs[SB][FF];
    const float4* xr4 = reinterpret_cast<const float4*>(x + (size_t)bat * (TT * FF));
    ST* __restrict__ prow = pre + ((size_t)(dir * NB + bat) * TT) * 256;

    for (int s0 = 0; s0 < TB; s0 += SB) {
        __syncthreads();   // protect xs reuse
        // stage SB rows of x (float4-coalesced)
        for (int i = tid; i < SB * (FF / 4); i += 256) {
            const int r = i / (FF / 4), q = i % (FF / 4);
            const int t  = t0 + s0 + r;
            const int te = dir ? (TT - 1 - t) : t;
            reinterpret_cast<float4*>(xs[r])[q] = xr4[(size_t)te * (FF / 4) + q];
        }
        __syncthreads();
        #pragma unroll 2
        for (int r = 0; r < SB; ++r) {
            const float4* xv = reinterpret_cast<const float4*>(xs[r]);
            float a0 = bias, a1 = 0.f, a2 = 0.f, a3 = 0.f;
            #pragma unroll
            for (int q = 0; q < FF / 4; ++q) {
                float4 v = xv[q];
                a0 = fmaf(wi4[q].x, v.x, a0);
                a1 = fmaf(wi4[q].y, v.y, a1);
                a2 = fmaf(wi4[q].z, v.z, a2);
                a3 = fmaf(wi4[q].w, v.w, a3);
            }
            stv(prow + (size_t)(t0 + s0 + r) * 256 + tid, (a0 + a1) + (a2 + a3));
        }
    }
}

// ---------------------------------------------------------------------------
// Recurrent scan with precomputed PRE. One block per (dir, batch), 256 threads,
// thread k owns gate k with its 64 W_hh weights truly register-resident.
// ---------------------------------------------------------------------------
template <typename ST>
__global__ __launch_bounds__(256, 1)
void lstm_scan_pre_kernel(const ST* __restrict__ pre,
                          const float* __restrict__ w_hh_f, const float* __restrict__ w_hh_b,
                          float* __restrict__ h_out)   // [2][NB][HH]
{
    const int blk = blockIdx.x;        // 0..255
    const int dir = blk >> 7;
    const int bat = blk & (NB - 1);
    const int tid = threadIdx.x;       // gate index k
    const int wv  = tid >> 6;
    const int ln  = tid & 63;

    const float* __restrict__ w_hh = dir ? w_hh_b : w_hh_f;
    float4 wh4[HH / 4];
    const float4* whr = reinterpret_cast<const float4*>(w_hh + tid * HH);
    #pragma unroll
    for (int j = 0; j < HH / 4; ++j) wh4[j] = whr[j];

    __shared__ float hbuf[4][HH];      // per-wave private h copy
    __shared__ float gbuf[2][256];     // pre-activation gates, double buffered

    float c = 0.0f, h = 0.0f;
    hbuf[wv][ln] = 0.0f;

    const ST* __restrict__ prow = pre + ((size_t)(dir * NB + bat) * TT) * 256 + tid;
    float p0 = ldv(prow);
    float p1 = ldv(prow + 256);
    __syncthreads();

    #pragma unroll 2
    for (int t = 0; t < TT; ++t) {
        const int cur = t & 1;
        float a0 = p0, a1 = 0.f, a2 = 0.f, a3 = 0.f;
        const float4* hb4 = reinterpret_cast<const float4*>(hbuf[wv]);
        #pragma unroll
        for (int j = 0; j < HH / 4; ++j) {
            float4 v = hb4[j];
            a0 = fmaf(wh4[j].x, v.x, a0);
            a1 = fmaf(wh4[j].y, v.y, a1);
            a2 = fmaf(wh4[j].z, v.z, a2);
            a3 = fmaf(wh4[j].w, v.w, a3);
        }
        gbuf[cur][tid] = (a0 + a1) + (a2 + a3);

        // rotate PRE prefetch pipeline (2 steps ahead covers global latency)
        p0 = p1;
        if (t + 2 < TT) p1 = ldv(prow + (size_t)(t + 2) * 256);

        __syncthreads();               // gates visible to all waves

        const float gi = gbuf[cur][ln];
        const float gf = gbuf[cur][64 + ln];
        const float gg = gbuf[cur][128 + ln];
        const float go = gbuf[cur][192 + ln];
        c = sigm(gf) * c + sigm(gi) * tanh_f(gg);
        h = sigm(go) * tanh_f(c);
        hbuf[wv][ln] = h;              // own-wave buffer: no 2nd barrier needed
    }

    if (tid < HH) h_out[(size_t)(dir * NB + bat) * HH + tid] = h;
}

// ---------------------------------------------------------------------------
// Fallback: fully fused scan (round-1 kernel) if ws is too small for PRE.
// ---------------------------------------------------------------------------
__global__ __launch_bounds__(256, 1)
void lstm_scan_fused_kernel(const float* __restrict__ x,
                            const float* __restrict__ w_ih_f, const float* __restrict__ w_hh_f,
                            const float* __restrict__ b_ih_f, const float* __restrict__ b_hh_f,
                            const float* __restrict__ w_ih_b, const float* __restrict__ w_hh_b,
                            const float* __restrict__ b_ih_b, const float* __restrict__ b_hh_b,
                            float* __restrict__ h_out)
{
    const int blk = blockIdx.x;
    const int dir = blk >> 7;
    const int bat = blk & 127;
    const int tid = threadIdx.x;
    const int wv  = tid >> 6;
    const int ln  = tid & 63;

    const float* __restrict__ w_ih = dir ? w_ih_b : w_ih_f;
    const float* __restrict__ w_hh = dir ? w_hh_b : w_hh_f;
    const float* __restrict__ b_ih = dir ? b_ih_b : b_ih_f;
    const float* __restrict__ b_hh = dir ? b_hh_b : b_hh_f;

    float wi[FF], wh[HH];
    #pragma unroll
    for (int f = 0; f < FF; ++f) wi[f] = w_ih[tid * FF + f];
    #pragma unroll
    for (int j = 0; j < HH; ++j) wh[j] = w_hh[tid * HH + j];
    const float bias = b_ih[tid] + b_hh[tid];

    __shared__ float xs[2][FF];
    __shared__ float hbuf[4][HH];
    __shared__ float gbuf[2][256];

    const float* __restrict__ xrow = x + (size_t)bat * (TT * FF);
    float c = 0.0f, hreg = 0.0f;
    hbuf[wv][ln] = 0.0f;

    float xA = 0.0f;
    if (tid < FF) {
        xs[0][tid] = xrow[(size_t)(dir ? (TT - 1) : 0) * FF + tid];
        xA         = xrow[(size_t)(dir ? (TT - 2) : 1) * FF + tid];
    }
    __syncthreads();

    #pragma unroll 1
    for (int t = 0; t < TT; ++t) {
        const int cur = t & 1, nxt = cur ^ 1;
        float a0 = 0.f, a1 = 0.f, a2 = 0.f, a3 = 0.f;
        const float4* xs4 = reinterpret_cast<const float4*>(xs[cur]);
        #pragma unroll
        for (int f = 0; f < FF / 4; ++f) {
            float4 v = xs4[f];
            a0 = fmaf(wi[4*f+0], v.x, a0);
            a1 = fmaf(wi[4*f+1], v.y, a1);
            a2 = fmaf(wi[4*f+2], v.z, a2);
            a3 = fmaf(wi[4*f+3], v.w, a3);
        }
        const float4* hb4 = reinterpret_cast<const float4*>(hbuf[wv]);
        #pragma unroll
        for (int j = 0; j < HH / 4; ++j) {
            float4 v = hb4[j];
            a0 = fmaf(wh[4*j+0], v.x, a0);
            a1 = fmaf(wh[4*j+1], v.y, a1);
            a2 = fmaf(wh[4*j+2], v.z, a2);
            a3 = fmaf(wh[4*j+3], v.w, a3);
        }
        gbuf[cur][tid] = ((a0 + a1) + (a2 + a3)) + bias;

        if (tid < FF) {
            if (t + 1 < TT) xs[nxt][tid] = xA;
            if (t + 2 < TT) xA = xrow[(size_t)(dir ? (TT - 3 - t) : (t + 2)) * FF + tid];
        }
        __syncthreads();

        const float gi = gbuf[cur][ln];
        const float gf = gbuf[cur][64 + ln];
        const float gg = gbuf[cur][128 + ln];
        const float go = gbuf[cur][192 + ln];
        c    = sigm(gf) * c + sigm(gi) * tanh_f(gg);
        hreg = sigm(go) * tanh_f(c);
        hbuf[wv][ln] = hreg;
    }

    if (tid < HH) h_out[(size_t)(dir * 128 + bat) * HH + tid] = hreg;
}

__global__ __launch_bounds__(64, 1)
void fc_kernel(const float* __restrict__ h_out,   // [2][NB][HH]
               const float* __restrict__ w_fc,    // [8][128]
               const float* __restrict__ b_fc,    // [8]
               float* __restrict__ out)           // [NB][8]
{
    const int b = blockIdx.x;
    const int o = threadIdx.x;
    if (o < 8) {
        float acc = b_fc[o];
        #pragma unroll 4
        for (int j = 0; j < HH; ++j)
            acc = fmaf(h_out[(size_t)b * HH + j], w_fc[o * 128 + j], acc);
        #pragma unroll 4
        for (int j = 0; j < HH; ++j)
            acc = fmaf(h_out[(size_t)(NB + b) * HH + j], w_fc[o * 128 + 64 + j], acc);
        out[b * 8 + o] = acc;
    }
}

extern "C" void kernel_launch(void* const* d_in, const int* in_sizes, int n_in,
                              void* d_out, int out_size, void* d_ws, size_t ws_size,
                              hipStream_t stream) {
    const float* x      = (const float*)d_in[0];
    const float* w_ih_f = (const float*)d_in[2];
    const float* w_hh_f = (const float*)d_in[3];
    const float* b_ih_f = (const float*)d_in[4];
    const float* b_hh_f = (const float*)d_in[5];
    const float* w_ih_b = (const float*)d_in[6];
    const float* w_hh_b = (const float*)d_in[7];
    const float* b_ih_b = (const float*)d_in[8];
    const float* b_hh_b = (const float*)d_in[9];
    const float* w_fc   = (const float*)d_in[10];
    const float* b_fc   = (const float*)d_in[11];
    float* out = (float*)d_out;

    const size_t pre_elems = (size_t)2 * NB * TT * 256;
    const size_t need_f32  = pre_elems * sizeof(float) + 64 * 1024;
    const size_t need_bf16 = pre_elems * sizeof(__hip_bfloat16) + 64 * 1024;
    const int    nproj     = 2 * NB * (TT / TB);   // 4096 blocks

    if (ws_size >= need_f32) {
        float* pre   = (float*)d_ws;
        float* h_out = (float*)((char*)d_ws + pre_elems * sizeof(float));
        lstm_proj_kernel<float><<<dim3(nproj), dim3(256), 0, stream>>>(
            x, w_ih_f, b_ih_f, b_hh_f, w_ih_b, b_ih_b, b_hh_b, pre);
        lstm_scan_pre_kernel<float><<<dim3(256), dim3(256), 0, stream>>>(
            pre, w_hh_f, w_hh_b, h_out);
        fc_kernel<<<dim3(128), dim3(64), 0, stream>>>(h_out, w_fc, b_fc, out);
    } else if (ws_size >= need_bf16) {
        __hip_bfloat16* pre = (__hip_bfloat16*)d_ws;
        float* h_out = (float*)((char*)d_ws + pre_elems * sizeof(__hip_bfloat16));
        lstm_proj_kernel<__hip_bfloat16><<<dim3(nproj), dim3(256), 0, stream>>>(
            x, w_ih_f, b_ih_f, b_hh_f, w_ih_b, b_ih_b, b_hh_b, pre);
        lstm_scan_pre_kernel<__hip_bfloat16><<<dim3(256), dim3(256), 0, stream>>>(
            pre, w_hh_f, w_hh_b, h_out);
        fc_kernel<<<dim3(128), dim3(64), 0, stream>>>(h_out, w_fc, b_fc, out);
    } else {
        float* h_out = (float*)d_ws;   // 64 KiB
        lstm_scan_fused_kernel<<<dim3(256), dim3(256), 0, stream>>>(
            x, w_ih_f, w_hh_f, b_ih_f, b_hh_f,
            w_ih_b, w_hh_b, b_ih_b, b_hh_b, h_out);
        fc_kernel<<<dim3(128), dim3(64), 0, stream>>>(h_out, w_fc, b_fc, out);
    }
}